// Round 9
// baseline (184.349 us; speedup 1.0000x reference)
//
#include <hip/hip_runtime.h>
#include <stdint.h>

// loss = 0.5*mean_i softplus(T - ||z_i||^2) + 0.5*mean_{i!=j} softplus(z_i.z_j - T)
// z = row-normalized emb (bf16). sim via MFMA, symmetric upper-triangle tiles only.
// softplus(x) ~= ln2 + x/2 + x^2*(1/8 + x^2*(-1/192 + x^2/2880)), |x|<=1.25.

#define TEMP 0.2f
#define NROW 8192
#define DIM  256
#define NT   32
#define BM   256
#define NBLK (NT * (NT + 1) / 2)

typedef __attribute__((ext_vector_type(8))) __bf16 bf16x8;
typedef __attribute__((ext_vector_type(4))) float  f32x4;

__device__ __forceinline__ unsigned short f2bf(float f) {
    unsigned int u = __float_as_uint(f);
    u += 0x7FFFu + ((u >> 16) & 1u);
    return (unsigned short)(u >> 16);
}

__device__ __forceinline__ float softplus_f(float x) {
    return __logf(1.0f + __expf(x));
}

__global__ __launch_bounds__(256) void k_normalize(const float* __restrict__ emb,
                                                   unsigned short* __restrict__ zb,
                                                   float* __restrict__ pos) {
    const int gw   = (int)((blockIdx.x * blockDim.x + threadIdx.x) >> 6);
    const int lane = threadIdx.x & 63;
    if (gw >= NROW) return;
    const float4* rp = (const float4*)(emb + (size_t)gw * DIM);
    float4 v = rp[lane];
    float ss = v.x * v.x + v.y * v.y + v.z * v.z + v.w * v.w;
#pragma unroll
    for (int off = 32; off >= 1; off >>= 1) ss += __shfl_xor(ss, off);
    float inv = 1.0f / fmaxf(sqrtf(ss), 1e-12f);
    ushort4 o;
    o.x = f2bf(v.x * inv); o.y = f2bf(v.y * inv);
    o.z = f2bf(v.z * inv); o.w = f2bf(v.w * inv);
    ((ushort4*)(zb + (size_t)gw * DIM))[lane] = o;
    if (lane == 0) pos[gw] = softplus_f(TEMP - ss * inv * inv);
}

__global__ __launch_bounds__(512, 2) void k_simloss(const unsigned short* __restrict__ zb,
                                                    float2* __restrict__ negp) {
    const int L = blockIdx.x;
    int br = (int)((65.0f - sqrtf(4225.0f - 8.0f * (float)L)) * 0.5f);
    while ((br + 1) * NT - ((br + 1) * br) / 2 <= L) ++br;
    while (br * NT - (br * (br - 1)) / 2 > L) --br;
    const int bc = br + (L - (br * NT - (br * (br - 1)) / 2));

    __shared__ __align__(128) unsigned char lds[131072];
    __shared__ float2 red[8];

    const int t    = threadIdx.x;
    const int lane = t & 63;
    const int w    = t >> 6;
    const int wr   = w >> 2, wc = w & 3;
    const int l15  = lane & 15;
    const int sw   = (lane & 7) << 4;
    const int q16  = (lane >> 4) << 4;

    const char* zbytes = (const char*)zb;
    const int srow = t >> 3;
    const int scol = ((t * 16) & 127) ^ ((srow & 7) << 4);

    f32x4 acc[8][4];
    const f32x4 z4 = {0.f, 0.f, 0.f, 0.f};
#pragma unroll
    for (int m = 0; m < 8; ++m)
#pragma unroll
        for (int n = 0; n < 4; ++n) acc[m][n] = z4;

    const size_t rowA0 = (size_t)br * BM, rowB0 = (size_t)bc * BM;

#define STAGE(buf, kt)                                                                     \
    {                                                                                      \
        unsigned char* dA = lds + (buf) * 65536 + t * 16;                                  \
        const char* sA = zbytes + (rowA0 + srow) * 512 + (kt) * 128 + scol;                \
        const char* sB = zbytes + (rowB0 + srow) * 512 + (kt) * 128 + scol;                \
        _Pragma("unroll")                                                                  \
        for (int it = 0; it < 4; ++it) {                                                   \
            __builtin_amdgcn_global_load_lds((const unsigned int*)(sA + it * 32768),       \
                                             (unsigned int*)(dA + it * 8192), 16, 0, 0);   \
            __builtin_amdgcn_global_load_lds((const unsigned int*)(sB + it * 32768),       \
                                             (unsigned int*)(dA + 32768 + it * 8192), 16, 0, 0); \
        }                                                                                  \
    }

    int cur = 0;
    STAGE(0, 0);
    __syncthreads();
#pragma unroll
    for (int kt = 0; kt < 4; ++kt) {
        if (kt < 3) STAGE(cur ^ 1, kt + 1);
        const unsigned char* Ab = lds + cur * 65536;
        const unsigned char* Bb = Ab + 32768;
#pragma unroll
        for (int ks = 0; ks < 2; ++ks) {
            const int off = (ks * 64 + q16) ^ sw;
            bf16x8 af[8], bfr[4];
#pragma unroll
            for (int m = 0; m < 8; ++m)
                af[m] = *(const bf16x8*)(Ab + (wr * 128 + m * 16 + l15) * 128 + off);
#pragma unroll
            for (int n = 0; n < 4; ++n)
                bfr[n] = *(const bf16x8*)(Bb + (wc * 64 + n * 16 + l15) * 128 + off);
#pragma unroll
            for (int m = 0; m < 8; ++m)
#pragma unroll
                for (int n = 0; n < 4; ++n)
                    acc[m][n] = __builtin_amdgcn_mfma_f32_16x16x32_bf16(af[m], bfr[n],
                                                                        acc[m][n], 0, 0, 0);
        }
        __syncthreads();
        cur ^= 1;
    }
#undef STAGE

    // branchless epilogue: mask diagonal via gi==gj select (diag only when br==bc)
    const float c2 = 0.125f, c4 = -1.0f / 192.0f, c6 = 1.0f / 2880.0f;
    float sum_x = 0.f, sum_p = 0.f;
    const bool dtile = (br == bc);
    const int gi0 = wr * 128 + ((lane >> 4) << 2);
    const int gj0 = wc * 64 + l15;
#pragma unroll 2
    for (int m = 0; m < 8; ++m)
#pragma unroll 2
        for (int n = 0; n < 4; ++n)
#pragma unroll 4
            for (int q = 0; q < 4; ++q) {
                float x = acc[m][n][q] - TEMP;
                x = (dtile && (gi0 + m * 16 + q) == (gj0 + n * 16)) ? 0.0f : x;
                sum_x += x;
                float u = x * x;
                float tp = fmaf(u, c6, c4);
                tp = fmaf(u, tp, c2);
                sum_p = fmaf(u, tp, sum_p);
            }
#pragma unroll
    for (int o = 32; o >= 1; o >>= 1) {
        sum_x += __shfl_xor(sum_x, o);
        sum_p += __shfl_xor(sum_p, o);
    }
    if (lane == 0) red[w] = make_float2(sum_x, sum_p);
    __syncthreads();
    if (t == 0) {
        float sx = 0.f, sp = 0.f;
#pragma unroll
        for (int i = 0; i < 8; ++i) { sx += red[i].x; sp += red[i].y; }
        const float sc = dtile ? 1.0f : 2.0f;
        negp[L] = make_float2(sx * sc, sp * sc);
    }
}

__global__ __launch_bounds__(256) void k_reduce(const float* __restrict__ pos,
                                                const float2* __restrict__ negp,
                                                float* __restrict__ out) {
    __shared__ double sd[3][256];
    const int t = threadIdx.x;
    double ps = 0.0, sx = 0.0, sp = 0.0;
    for (int i = t; i < NROW; i += 256) ps += (double)pos[i];
    for (int i = t; i < NBLK; i += 256) { float2 v = negp[i]; sx += (double)v.x; sp += (double)v.y; }
    sd[0][t] = ps; sd[1][t] = sx; sd[2][t] = sp;
    __syncthreads();
    for (int s = 128; s >= 1; s >>= 1) {
        if (t < s) {
            sd[0][t] += sd[0][t + s];
            sd[1][t] += sd[1][t + s];
            sd[2][t] += sd[2][t + s];
        }
        __syncthreads();
    }
    if (t == 0) {
        const double CNT = (double)NROW * (double)(NROW - 1);
        double neg_mean = 0.6931471805599453 + (0.5 * sd[1][0] + sd[2][0]) / CNT;
        double pos_mean = sd[0][0] / (double)NROW;
        out[0] = (float)(0.5 * pos_mean + 0.5 * neg_mean);
    }
}

extern "C" void kernel_launch(void* const* d_in, const int* in_sizes, int n_in,
                              void* d_out, int out_size, void* d_ws, size_t ws_size,
                              hipStream_t stream) {
    const float* emb = (const float*)d_in[0];
    float* out = (float*)d_out;

    unsigned short* zb = (unsigned short*)d_ws;
    float* pos   = (float*)((char*)d_ws + (size_t)NROW * DIM * 2);
    float2* negp = (float2*)(pos + NROW);

    k_normalize<<<NROW / 4, 256, 0, stream>>>(emb, zb, pos);
    k_simloss<<<NBLK, 512, 0, stream>>>(zb, negp);
    k_reduce<<<1, 256, 0, stream>>>(pos, negp, out);
}

// Round 10
// 48.031 us; speedup vs baseline: 3.8381x; 3.8381x over previous
//
#include <hip/hip_runtime.h>
#include <stdint.h>

// loss = 0.5*mean_i softplus(T - ||z_i||^2) + 0.5*mean_{i!=j} softplus(z_i.z_j - T)
// z = row-normalized emb (bf16). sim via MFMA, symmetric upper-triangle tiles only.
// softplus(x) ~= ln2 + x/2 + x^2*(1/8 + x^2*(-1/192 + x^2/2880)), |x|<=1.25.
// NOTE: epilogue loops MUST be fully unrolled — partial unroll leaves runtime
// indices into acc[][] and spills the whole accumulator to scratch (rule #20;
// round-9 counters: WRITE_SIZE 659MB, MfmaUtil 0.09%).

#define TEMP 0.2f
#define NROW 8192
#define DIM  256
#define NT   32
#define BM   256
#define NBLK (NT * (NT + 1) / 2)

typedef __attribute__((ext_vector_type(8))) __bf16 bf16x8;
typedef __attribute__((ext_vector_type(4))) float  f32x4;

__device__ __forceinline__ unsigned short f2bf(float f) {
    unsigned int u = __float_as_uint(f);
    u += 0x7FFFu + ((u >> 16) & 1u);
    return (unsigned short)(u >> 16);
}

__device__ __forceinline__ float softplus_f(float x) {
    return __logf(1.0f + __expf(x));
}

__global__ __launch_bounds__(256) void k_normalize(const float* __restrict__ emb,
                                                   unsigned short* __restrict__ zb,
                                                   float* __restrict__ pos) {
    const int gw   = (int)((blockIdx.x * blockDim.x + threadIdx.x) >> 6);
    const int lane = threadIdx.x & 63;
    if (gw >= NROW) return;
    const float4* rp = (const float4*)(emb + (size_t)gw * DIM);
    float4 v = rp[lane];
    float ss = v.x * v.x + v.y * v.y + v.z * v.z + v.w * v.w;
#pragma unroll
    for (int off = 32; off >= 1; off >>= 1) ss += __shfl_xor(ss, off);
    float inv = 1.0f / fmaxf(sqrtf(ss), 1e-12f);
    ushort4 o;
    o.x = f2bf(v.x * inv); o.y = f2bf(v.y * inv);
    o.z = f2bf(v.z * inv); o.w = f2bf(v.w * inv);
    ((ushort4*)(zb + (size_t)gw * DIM))[lane] = o;
    if (lane == 0) pos[gw] = softplus_f(TEMP - ss * inv * inv);
}

__global__ __launch_bounds__(512, 2) void k_simloss(const unsigned short* __restrict__ zb,
                                                    float2* __restrict__ negp) {
    const int L = blockIdx.x;
    int br = (int)((65.0f - sqrtf(4225.0f - 8.0f * (float)L)) * 0.5f);
    while ((br + 1) * NT - ((br + 1) * br) / 2 <= L) ++br;
    while (br * NT - (br * (br - 1)) / 2 > L) --br;
    const int bc = br + (L - (br * NT - (br * (br - 1)) / 2));

    __shared__ __align__(128) unsigned char lds[131072];
    __shared__ float2 red[8];

    const int t    = threadIdx.x;
    const int lane = t & 63;
    const int w    = t >> 6;
    const int wr   = w >> 2, wc = w & 3;
    const int l15  = lane & 15;
    const int sw   = (lane & 7) << 4;
    const int q16  = (lane >> 4) << 4;

    const char* zbytes = (const char*)zb;
    const int srow = t >> 3;
    const int scol = ((t * 16) & 127) ^ ((srow & 7) << 4);

    f32x4 acc[8][4];
    const f32x4 z4 = {0.f, 0.f, 0.f, 0.f};
#pragma unroll
    for (int m = 0; m < 8; ++m)
#pragma unroll
        for (int n = 0; n < 4; ++n) acc[m][n] = z4;

    const size_t rowA0 = (size_t)br * BM, rowB0 = (size_t)bc * BM;

#define STAGE(buf, kt)                                                                     \
    {                                                                                      \
        unsigned char* dA = lds + (buf) * 65536 + t * 16;                                  \
        const char* sA = zbytes + (rowA0 + srow) * 512 + (kt) * 128 + scol;                \
        const char* sB = zbytes + (rowB0 + srow) * 512 + (kt) * 128 + scol;                \
        _Pragma("unroll")                                                                  \
        for (int it = 0; it < 4; ++it) {                                                   \
            __builtin_amdgcn_global_load_lds((const unsigned int*)(sA + it * 32768),       \
                                             (unsigned int*)(dA + it * 8192), 16, 0, 0);   \
            __builtin_amdgcn_global_load_lds((const unsigned int*)(sB + it * 32768),       \
                                             (unsigned int*)(dA + 32768 + it * 8192), 16, 0, 0); \
        }                                                                                  \
    }

    int cur = 0;
    STAGE(0, 0);
    __syncthreads();
#pragma unroll
    for (int kt = 0; kt < 4; ++kt) {
        if (kt < 3) STAGE(cur ^ 1, kt + 1);
        const unsigned char* Ab = lds + cur * 65536;
        const unsigned char* Bb = Ab + 32768;
#pragma unroll
        for (int ks = 0; ks < 2; ++ks) {
            const int off = (ks * 64 + q16) ^ sw;
            bf16x8 af[8], bfr[4];
#pragma unroll
            for (int m = 0; m < 8; ++m)
                af[m] = *(const bf16x8*)(Ab + (wr * 128 + m * 16 + l15) * 128 + off);
#pragma unroll
            for (int n = 0; n < 4; ++n)
                bfr[n] = *(const bf16x8*)(Bb + (wc * 64 + n * 16 + l15) * 128 + off);
#pragma unroll
            for (int m = 0; m < 8; ++m)
#pragma unroll
                for (int n = 0; n < 4; ++n)
                    acc[m][n] = __builtin_amdgcn_mfma_f32_16x16x32_bf16(af[m], bfr[n],
                                                                        acc[m][n], 0, 0, 0);
        }
        __syncthreads();
        cur ^= 1;
    }
#undef STAGE

    // branchless epilogue: FULLY unrolled (compile-time acc indices only)
    const float c2 = 0.125f, c4 = -1.0f / 192.0f, c6 = 1.0f / 2880.0f;
    float sum_x = 0.f, sum_p = 0.f;
    const bool dtile = (br == bc);
    const int gi0 = wr * 128 + ((lane >> 4) << 2);
    const int gj0 = wc * 64 + l15;
#pragma unroll
    for (int m = 0; m < 8; ++m)
#pragma unroll
        for (int n = 0; n < 4; ++n)
#pragma unroll
            for (int q = 0; q < 4; ++q) {
                float x = acc[m][n][q] - TEMP;
                x = (dtile && (gi0 + m * 16 + q) == (gj0 + n * 16)) ? 0.0f : x;
                sum_x += x;
                float u = x * x;
                float tp = fmaf(u, c6, c4);
                tp = fmaf(u, tp, c2);
                sum_p = fmaf(u, tp, sum_p);
            }
#pragma unroll
    for (int o = 32; o >= 1; o >>= 1) {
        sum_x += __shfl_xor(sum_x, o);
        sum_p += __shfl_xor(sum_p, o);
    }
    if (lane == 0) red[w] = make_float2(sum_x, sum_p);
    __syncthreads();
    if (t == 0) {
        float sx = 0.f, sp = 0.f;
#pragma unroll
        for (int i = 0; i < 8; ++i) { sx += red[i].x; sp += red[i].y; }
        const float sc = dtile ? 1.0f : 2.0f;
        negp[L] = make_float2(sx * sc, sp * sc);
    }
}

__global__ __launch_bounds__(256) void k_reduce(const float* __restrict__ pos,
                                                const float2* __restrict__ negp,
                                                float* __restrict__ out) {
    __shared__ double sd[3][256];
    const int t = threadIdx.x;
    double ps = 0.0, sx = 0.0, sp = 0.0;
    for (int i = t; i < NROW; i += 256) ps += (double)pos[i];
    for (int i = t; i < NBLK; i += 256) { float2 v = negp[i]; sx += (double)v.x; sp += (double)v.y; }
    sd[0][t] = ps; sd[1][t] = sx; sd[2][t] = sp;
    __syncthreads();
    for (int s = 128; s >= 1; s >>= 1) {
        if (t < s) {
            sd[0][t] += sd[0][t + s];
            sd[1][t] += sd[1][t + s];
            sd[2][t] += sd[2][t + s];
        }
        __syncthreads();
    }
    if (t == 0) {
        const double CNT = (double)NROW * (double)(NROW - 1);
        double neg_mean = 0.6931471805599453 + (0.5 * sd[1][0] + sd[2][0]) / CNT;
        double pos_mean = sd[0][0] / (double)NROW;
        out[0] = (float)(0.5 * pos_mean + 0.5 * neg_mean);
    }
}

extern "C" void kernel_launch(void* const* d_in, const int* in_sizes, int n_in,
                              void* d_out, int out_size, void* d_ws, size_t ws_size,
                              hipStream_t stream) {
    const float* emb = (const float*)d_in[0];
    float* out = (float*)d_out;

    unsigned short* zb = (unsigned short*)d_ws;
    float* pos   = (float*)((char*)d_ws + (size_t)NROW * DIM * 2);
    float2* negp = (float2*)(pos + NROW);

    k_normalize<<<NROW / 4, 256, 0, stream>>>(emb, zb, pos);
    k_simloss<<<NBLK, 512, 0, stream>>>(zb, negp);
    k_reduce<<<1, 256, 0, stream>>>(pos, negp, out);
}